// Round 1
// baseline (370.501 us; speedup 1.0000x reference)
//
#include <hip/hip_runtime.h>

typedef __attribute__((ext_vector_type(8))) short short8;
typedef __attribute__((ext_vector_type(4))) float f32x4;
typedef __attribute__((ext_vector_type(4))) unsigned short ushort4v;

#define HIDDEN 1024
#define NHEAD 16
#define HD 64
#define BATCH 2
#define SEQ 2048
#define MROWS (BATCH * SEQ)  // 4096

__device__ __forceinline__ unsigned short f2b(float f) {
  union { float f; unsigned u; } v; v.f = f;
  unsigned r = v.u + 0x7fffu + ((v.u >> 16) & 1u);
  return (unsigned short)(r >> 16);
}

// ---------------- f32 -> bf16 convert ----------------
__global__ void cvt_bf16_kernel(const float* __restrict__ in,
                                unsigned short* __restrict__ out, int n) {
  int i = (blockIdx.x * blockDim.x + threadIdx.x) * 4;
  if (i >= n) return;
  float4 v = *reinterpret_cast<const float4*>(in + i);
  ushort4v o;
  o.x = f2b(v.x); o.y = f2b(v.y); o.z = f2b(v.z); o.w = f2b(v.w);
  *reinterpret_cast<ushort4v*>(out + i) = o;
}

// ---------------- GEMM: C[M][N] = A[M][K] * B[N][K]^T (+bias), mode epilogue ----
// mode 0: Q -> bf16 [B,H,S,D], (acc+bias)*0.125
// mode 1: K -> bf16 [B,H,S,D]
// mode 2: V -> bf16 [B,H,D,S] (transposed)
// mode 3: O -> f32 [M][N] to d_out
__global__ __launch_bounds__(256) void gemm_bt_kernel(
    const unsigned short* __restrict__ A, const unsigned short* __restrict__ Bm,
    const float* __restrict__ bias, void* __restrict__ outp, int M, int K,
    int mode) {
  __shared__ unsigned short Al[64][72];  // +8 pad: row stride 144B (16B-aligned)
  __shared__ unsigned short Bl[64][72];
  const int t = threadIdx.x;
  const int w = t >> 6;
  const int l = t & 63;
  const int m0 = blockIdx.x * 64;
  const int n0 = blockIdx.y * 64;

  f32x4 acc[4];
#pragma unroll
  for (int f = 0; f < 4; ++f) acc[f] = f32x4{0.f, 0.f, 0.f, 0.f};

  for (int kt = 0; kt < K; kt += 64) {
    __syncthreads();
#pragma unroll
    for (int p = 0; p < 2; ++p) {
      int idx = p * 256 + t;
      int row = idx >> 3, cb = idx & 7;
      *reinterpret_cast<short8*>(&Al[row][cb * 8]) =
          *reinterpret_cast<const short8*>(A + (size_t)(m0 + row) * K + kt + cb * 8);
      *reinterpret_cast<short8*>(&Bl[row][cb * 8]) =
          *reinterpret_cast<const short8*>(Bm + (size_t)(n0 + row) * K + kt + cb * 8);
    }
    __syncthreads();
#pragma unroll
    for (int kk = 0; kk < 2; ++kk) {
      short8 af = *reinterpret_cast<const short8*>(&Al[w * 16 + (l & 15)][kk * 32 + (l >> 4) * 8]);
#pragma unroll
      for (int f = 0; f < 4; ++f) {
        short8 bf = *reinterpret_cast<const short8*>(&Bl[f * 16 + (l & 15)][kk * 32 + (l >> 4) * 8]);
        acc[f] = __builtin_amdgcn_mfma_f32_16x16x32_bf16(af, bf, acc[f], 0, 0, 0);
      }
    }
  }

#pragma unroll
  for (int f = 0; f < 4; ++f)
#pragma unroll
    for (int j = 0; j < 4; ++j) {
      int m = m0 + w * 16 + (l >> 4) * 4 + j;
      int n = n0 + f * 16 + (l & 15);
      float v = acc[f][j] + bias[n];
      if (mode <= 1) {
        if (mode == 0) v *= 0.125f;  // 1/sqrt(64)
        int b = m >> 11, s = m & 2047, h = n >> 6, d = n & 63;
        ((unsigned short*)outp)[((size_t)(b * NHEAD + h) * SEQ + s) * HD + d] = f2b(v);
      } else if (mode == 2) {
        int b = m >> 11, s = m & 2047, h = n >> 6, d = n & 63;
        ((unsigned short*)outp)[((size_t)(b * NHEAD + h) * HD + d) * SEQ + s] = f2b(v);
      } else {
        ((float*)outp)[(size_t)m * HIDDEN + n] = v;
      }
    }
}

// ---------------- flash attention ----------------
// Q,K: bf16 [B*H][S][64]; Vt: bf16 [B*H][64][S]; mask: int [B][S]
// O: bf16 [B*S][HIDDEN]
__global__ __launch_bounds__(256) void attn_kernel(
    const unsigned short* __restrict__ Q, const unsigned short* __restrict__ Km,
    const unsigned short* __restrict__ Vt, const int* __restrict__ mask,
    unsigned short* __restrict__ O) {
  __shared__ unsigned short Pl[4][16][72];
  const int t = threadIdx.x;
  const int w = t >> 6;
  const int l = t & 63;
  const int bh = blockIdx.y;
  const int b = bh >> 4, h = bh & 15;
  const int q0 = blockIdx.x * 64 + w * 16;

  const unsigned short* Qb = Q + (size_t)bh * SEQ * HD;
  const unsigned short* Kb = Km + (size_t)bh * SEQ * HD;
  const unsigned short* Vb = Vt + (size_t)bh * HD * SEQ;
  const int* mb = mask + b * SEQ;

  short8 qf[2];
#pragma unroll
  for (int kk = 0; kk < 2; ++kk)
    qf[kk] = *reinterpret_cast<const short8*>(Qb + (size_t)(q0 + (l & 15)) * HD + kk * 32 + (l >> 4) * 8);

  f32x4 o_acc[4];
#pragma unroll
  for (int f = 0; f < 4; ++f) o_acc[f] = f32x4{0.f, 0.f, 0.f, 0.f};
  float mrow[4], srow[4];
#pragma unroll
  for (int j = 0; j < 4; ++j) { mrow[j] = -1e30f; srow[j] = 0.f; }

  const int qrow_base = q0 + ((l >> 4) << 2);  // + j = this lane's q rows

  for (int k0 = 0; k0 < SEQ; k0 += 64) {
    f32x4 sc[4];
#pragma unroll
    for (int f = 0; f < 4; ++f) sc[f] = f32x4{0.f, 0.f, 0.f, 0.f};
#pragma unroll
    for (int kk = 0; kk < 2; ++kk)
#pragma unroll
      for (int f = 0; f < 4; ++f) {
        short8 kf = *reinterpret_cast<const short8*>(
            Kb + (size_t)(k0 + f * 16 + (l & 15)) * HD + kk * 32 + (l >> 4) * 8);
        sc[f] = __builtin_amdgcn_mfma_f32_16x16x32_bf16(qf[kk], kf, sc[f], 0, 0, 0);
      }

    // mask: key masked unless it is the diagonal (k==q)
    int kcol[4], msk[4];
#pragma unroll
    for (int f = 0; f < 4; ++f) {
      kcol[f] = k0 + f * 16 + (l & 15);
      msk[f] = mb[kcol[f]];
    }
    float tmax[4];
#pragma unroll
    for (int j = 0; j < 4; ++j) {
      int qrow = qrow_base + j;
      float mx = -1e30f;
#pragma unroll
      for (int f = 0; f < 4; ++f) {
        float v = sc[f][j];
        if (msk[f] && (kcol[f] != qrow)) v = -1e30f;
        sc[f][j] = v;
        mx = fmaxf(mx, v);
      }
      tmax[j] = mx;
    }
#pragma unroll
    for (int off = 1; off < 16; off <<= 1)
#pragma unroll
      for (int j = 0; j < 4; ++j)
        tmax[j] = fmaxf(tmax[j], __shfl_xor(tmax[j], off, 64));

    float pscale[4];
#pragma unroll
    for (int j = 0; j < 4; ++j) {
      float mnew = fmaxf(mrow[j], tmax[j]);
      pscale[j] = __expf(mrow[j] - mnew);
      mrow[j] = mnew;
    }
    float tsum[4] = {0.f, 0.f, 0.f, 0.f};
#pragma unroll
    for (int f = 0; f < 4; ++f)
#pragma unroll
      for (int j = 0; j < 4; ++j) {
        float p = __expf(sc[f][j] - mrow[j]);
        sc[f][j] = p;
        tsum[j] += p;
      }
#pragma unroll
    for (int off = 1; off < 16; off <<= 1)
#pragma unroll
      for (int j = 0; j < 4; ++j) tsum[j] += __shfl_xor(tsum[j], off, 64);
#pragma unroll
    for (int j = 0; j < 4; ++j) srow[j] = srow[j] * pscale[j] + tsum[j];
#pragma unroll
    for (int f = 0; f < 4; ++f)
#pragma unroll
      for (int j = 0; j < 4; ++j) o_acc[f][j] *= pscale[j];

    __syncthreads();  // previous PV reads done before overwrite
#pragma unroll
    for (int f = 0; f < 4; ++f)
#pragma unroll
      for (int j = 0; j < 4; ++j)
        Pl[w][(l >> 4) * 4 + j][f * 16 + (l & 15)] = f2b(sc[f][j]);
    __syncthreads();  // P visible before fragment reads

#pragma unroll
    for (int kk = 0; kk < 2; ++kk) {
      short8 pf = *reinterpret_cast<const short8*>(&Pl[w][l & 15][kk * 32 + (l >> 4) * 8]);
#pragma unroll
      for (int f = 0; f < 4; ++f) {
        short8 vf = *reinterpret_cast<const short8*>(
            Vb + (size_t)(f * 16 + (l & 15)) * SEQ + k0 + kk * 32 + (l >> 4) * 8);
        o_acc[f] = __builtin_amdgcn_mfma_f32_16x16x32_bf16(pf, vf, o_acc[f], 0, 0, 0);
      }
    }
  }

#pragma unroll
  for (int f = 0; f < 4; ++f)
#pragma unroll
    for (int j = 0; j < 4; ++j) {
      int qrow = qrow_base + j;
      float v = o_acc[f][j] / srow[j];
      O[((size_t)(b * SEQ + qrow)) * HIDDEN + h * HD + f * 16 + (l & 15)] = f2b(v);
    }
}

// ---------------- launch ----------------
extern "C" void kernel_launch(void* const* d_in, const int* in_sizes, int n_in,
                              void* d_out, int out_size, void* d_ws,
                              size_t ws_size, hipStream_t stream) {
  const float* x = (const float*)d_in[0];
  const int* mask = (const int*)d_in[1];
  const float* Wq = (const float*)d_in[2];
  const float* bq = (const float*)d_in[3];
  const float* Wk = (const float*)d_in[4];
  const float* bk = (const float*)d_in[5];
  const float* Wv = (const float*)d_in[6];
  const float* bv = (const float*)d_in[7];
  const float* Wo = (const float*)d_in[8];
  const float* bo = (const float*)d_in[9];

  char* ws = (char*)d_ws;
  unsigned short* xb  = (unsigned short*)(ws + ((size_t)0 << 20));   // 8 MB
  unsigned short* wqb = (unsigned short*)(ws + ((size_t)8 << 20));   // 2 MB
  unsigned short* wkb = (unsigned short*)(ws + ((size_t)10 << 20));
  unsigned short* wvb = (unsigned short*)(ws + ((size_t)12 << 20));
  unsigned short* wob = (unsigned short*)(ws + ((size_t)14 << 20));
  unsigned short* qw  = (unsigned short*)(ws + ((size_t)16 << 20));  // 8 MB
  unsigned short* kw  = (unsigned short*)(ws + ((size_t)24 << 20));
  unsigned short* vtw = (unsigned short*)(ws + ((size_t)32 << 20));
  unsigned short* ow  = (unsigned short*)(ws + ((size_t)40 << 20));

  const int nx = MROWS * HIDDEN;
  const int nw = HIDDEN * HIDDEN;
  cvt_bf16_kernel<<<nx / 4 / 256, 256, 0, stream>>>(x, xb, nx);
  cvt_bf16_kernel<<<nw / 4 / 256, 256, 0, stream>>>(Wq, wqb, nw);
  cvt_bf16_kernel<<<nw / 4 / 256, 256, 0, stream>>>(Wk, wkb, nw);
  cvt_bf16_kernel<<<nw / 4 / 256, 256, 0, stream>>>(Wv, wvb, nw);
  cvt_bf16_kernel<<<nw / 4 / 256, 256, 0, stream>>>(Wo, wob, nw);

  dim3 gg(MROWS / 64, HIDDEN / 64);
  gemm_bt_kernel<<<gg, 256, 0, stream>>>(xb, wqb, bq, qw, MROWS, HIDDEN, 0);
  gemm_bt_kernel<<<gg, 256, 0, stream>>>(xb, wkb, bk, kw, MROWS, HIDDEN, 1);
  gemm_bt_kernel<<<gg, 256, 0, stream>>>(xb, wvb, bv, vtw, MROWS, HIDDEN, 2);

  attn_kernel<<<dim3(SEQ / 64, BATCH * NHEAD), 256, 0, stream>>>(qw, kw, vtw, mask, ow);

  gemm_bt_kernel<<<gg, 256, 0, stream>>>(ow, wob, bo, d_out, MROWS, HIDDEN, 3);
}